// Round 7
// baseline (1185.097 us; speedup 1.0000x reference)
//
#include <hip/hip_runtime.h>
#include <hip/hip_bf16.h>
#include <math.h>

#define B_N 32768
#define COORD 64
#define DG 2048
#define CA 256
#define K_ACT 81
#define SETTLE_STEPS 5
#define GAIN 0.7f
#define LN_EPS 1e-5f
#define COS_EPS 1e-8f

typedef __attribute__((ext_vector_type(8))) short short8v;
typedef __attribute__((ext_vector_type(4))) float f32x4;

__device__ __forceinline__ float wave_sum(float v) {
#pragma unroll
  for (int d = 1; d < 64; d <<= 1) v += __shfl_xor(v, d);
  return v;
}

__device__ __forceinline__ float dot4(float4 a, float4 b) {
  return a.x * b.x + a.y * b.y + a.z * b.z + a.w * b.w;
}

__device__ __forceinline__ void fma4(float4& a, float s, float4 w) {
  a.x += s * w.x; a.y += s * w.y; a.z += s * w.z; a.w += s * w.w;
}

__device__ __forceinline__ float fast_tanh(float x) {
  float e = __expf(2.0f * x);
  return 1.0f - 2.0f / (e + 1.0f);
}

__device__ __forceinline__ unsigned int okey(float f) {
  unsigned int u = __float_as_uint(f);
  return (u & 0x80000000u) ? ~u : (u | 0x80000000u);
}

// bf16 round-to-nearest-even split helpers
__device__ __forceinline__ ushort f2bf(float f) {
  unsigned u = __float_as_uint(f);
  unsigned r = (u + 0x7FFFu + ((u >> 16) & 1u)) >> 16;
  return (ushort)r;
}
__device__ __forceinline__ float bf2f(ushort h) {
  return __uint_as_float(((unsigned)h) << 16);
}

// ---- column sums of coords (for buf) ----
__global__ void colsum_kernel(const float* __restrict__ coords,
                              float* __restrict__ colsum) {
  int tid = threadIdx.x;
  int col = tid & 63;
  int rg = tid >> 6;
  float s = 0.f;
  int base = blockIdx.x * 128;
#pragma unroll 4
  for (int i = 0; i < 32; ++i) {
    int r = base + rg + i * 4;
    s += coords[r * COORD + col];
  }
  __shared__ float sh[256];
  sh[tid] = s;
  __syncthreads();
  if (tid < 64) {
    float t = sh[tid] + sh[tid + 64] + sh[tid + 128] + sh[tid + 192];
    atomicAdd(&colsum[tid], t);
  }
}

// ---- generic transpose: T[c*R + r] = S[r*C + c] ----
__global__ void transpose_any(const float* __restrict__ S,
                              float* __restrict__ T, int R, int C) {
  int idx = blockIdx.x * 256 + threadIdx.x;
  if (idx < R * C) {
    int r = idx / C, c = idx - r * C;
    T[c * R + r] = S[r * C + c];
  }
}

// ---- elementwise bf16 hi/lo split ----
__global__ void split_bf16(const float* __restrict__ S, ushort* __restrict__ H,
                           ushort* __restrict__ L, int n) {
  int i = blockIdx.x * 256 + threadIdx.x;
  if (i < n) {
    float v = S[i];
    ushort h = f2bf(v);
    H[i] = h;
    L[i] = f2bf(v - bf2f(h));
  }
}

// ---- fused-weight precompute: F[out][in] = dot(A[out,:], BT[in,:]) (K=256),
// emitted as row-major bf16 hi/lo; cvec[out] = dot(A[out,:], bvec).
__global__ void fuse_mm_bf16(const float* __restrict__ A,
                             const float* __restrict__ BT,
                             const float* __restrict__ bvec,
                             ushort* __restrict__ Fh, ushort* __restrict__ Fl,
                             float* __restrict__ cvec, int IN) {
  __shared__ float brow[256];
  int in = blockIdx.x, outp = threadIdx.x;
  brow[outp] = BT[in * 256 + outp];
  __syncthreads();
  const float* arow = A + outp * 256;
  float acc = 0.f;
#pragma unroll 4
  for (int k = 0; k < 256; ++k) acc += arow[k] * brow[k];
  ushort h = f2bf(acc);
  Fh[outp * IN + in] = h;
  Fl[outp * IN + in] = f2bf(acc - bf2f(h));
  if (in == 0) {
    float b = 0.f;
#pragma unroll 4
    for (int k = 0; k < 256; ++k) b += arow[k] * bvec[k];
    cvec[outp] = b;
  }
}

// ============ mega1: EC-LN -> proj(+LN) -> radix top-81 -> cue ============
// (unchanged from round 3 — fp32-exact, top-k tie semantics preserved)
__global__ __launch_bounds__(512, 4) void mega1(
    const float* __restrict__ coords, const float* __restrict__ colsum,
    const float* __restrict__ ec_gamma, const float* __restrict__ ec_beta,
    const float* __restrict__ W_ppT, const float* __restrict__ b_pp,
    const float* __restrict__ dg_gamma, const float* __restrict__ dg_beta,
    const float* __restrict__ WmT, float* __restrict__ cue_g) {
  __shared__ __align__(16) float proj_s[8][DG];
  __shared__ __align__(16) float ec_s[8][COORD];
  __shared__ unsigned int hist[8][256];
  __shared__ float psum_s[8][8], psq_s[8][8];
  __shared__ int sel_s[8][88];

  const int w = threadIdx.x >> 6;
  const int l = threadIdx.x & 63;
  const int row0 = blockIdx.x * 8;

  {
    int row = row0 + w;
    float x = coords[row * COORD + l] + (0.05f / (float)B_N) * colsum[l];
    float mu = wave_sum(x) * (1.f / 64.f);
    float d = x - mu;
    float var = wave_sum(d * d) * (1.f / 64.f);
    ec_s[w][l] = d * rsqrtf(var + LN_EPS) * ec_gamma[l] + ec_beta[l];
  }
  __syncthreads();

  {
    float4 acc[8];
#pragma unroll
    for (int r = 0; r < 8; ++r) acc[r] = make_float4(0.f, 0.f, 0.f, 0.f);
    const float4* wp4 = reinterpret_cast<const float4*>(W_ppT);
    const int cbase = 64 * w + l;
    for (int kg = 0; kg < 16; ++kg) {
      float4 w40 = wp4[(4 * kg + 0) * 512 + cbase];
      float4 w41 = wp4[(4 * kg + 1) * 512 + cbase];
      float4 w42 = wp4[(4 * kg + 2) * 512 + cbase];
      float4 w43 = wp4[(4 * kg + 3) * 512 + cbase];
#pragma unroll
      for (int r = 0; r < 8; ++r) {
        float4 e4 = reinterpret_cast<const float4*>(ec_s[r])[kg];
        fma4(acc[r], e4.x, w40);
        fma4(acc[r], e4.y, w41);
        fma4(acc[r], e4.z, w42);
        fma4(acc[r], e4.w, w43);
      }
    }
    float4 bp = reinterpret_cast<const float4*>(b_pp)[cbase];
#pragma unroll
    for (int r = 0; r < 8; ++r) {
      float4 h;
      h.x = fmaxf(acc[r].x + bp.x, 0.f);
      h.y = fmaxf(acc[r].y + bp.y, 0.f);
      h.z = fmaxf(acc[r].z + bp.z, 0.f);
      h.w = fmaxf(acc[r].w + bp.w, 0.f);
      reinterpret_cast<float4*>(proj_s[r])[cbase] = h;
      float ps = wave_sum(h.x + h.y + h.z + h.w);
      float pq = wave_sum(dot4(h, h));
      if (l == 0) { psum_s[w][r] = ps; psq_s[w][r] = pq; }
    }
  }
  __syncthreads();

  float mu2, rs2;
  {
    float s = 0.f, q = 0.f;
#pragma unroll
    for (int w2 = 0; w2 < 8; ++w2) { s += psum_s[w2][w]; q += psq_s[w2][w]; }
    mu2 = s * (1.f / (float)DG);
    float var = q * (1.f / (float)DG) - mu2 * mu2;
    rs2 = rsqrtf(var + LN_EPS);
  }
  unsigned int key[32];
#pragma unroll 4
  for (int i = 0; i < 32; ++i) {
    int j = i * 64 + l;
    float v = (proj_s[w][j] - mu2) * rs2 * dg_gamma[j] + dg_beta[j];
    proj_s[w][j] = v;
    key[i] = okey(v);
  }

  unsigned int prefix = 0, rem = K_ACT;
#pragma unroll 1
  for (int pass = 0; pass < 4; ++pass) {
    int sh = 24 - 8 * pass;
#pragma unroll
    for (int b = l; b < 256; b += 64) hist[w][b] = 0;
#pragma unroll 4
    for (int i = 0; i < 32; ++i) {
      unsigned int k = key[i];
      bool ok = (pass == 0) || ((k >> (sh + 8)) == prefix);
      if (ok) atomicAdd(&hist[w][(k >> sh) & 255u], 1u);
    }
    unsigned int h0 = hist[w][4 * l + 0], h1 = hist[w][4 * l + 1];
    unsigned int h2 = hist[w][4 * l + 2], h3 = hist[w][4 * l + 3];
    unsigned int own = h0 + h1 + h2 + h3;
    unsigned int inc = own;
#pragma unroll
    for (int d = 1; d < 64; d <<= 1) {
      unsigned int v = __shfl_down(inc, d);
      if (l + d < 64) inc += v;
    }
    unsigned int cnt = inc - own;
    unsigned int pk = 0;
    {
      unsigned int hb;
      hb = h3; if (cnt < rem && rem <= cnt + hb) pk = ((rem - cnt) << 8) | (unsigned)(4 * l + 3); cnt += hb;
      hb = h2; if (cnt < rem && rem <= cnt + hb) pk = ((rem - cnt) << 8) | (unsigned)(4 * l + 2); cnt += hb;
      hb = h1; if (cnt < rem && rem <= cnt + hb) pk = ((rem - cnt) << 8) | (unsigned)(4 * l + 1); cnt += hb;
      hb = h0; if (cnt < rem && rem <= cnt + hb) pk = ((rem - cnt) << 8) | (unsigned)(4 * l + 0); cnt += hb;
    }
#pragma unroll
    for (int d = 1; d < 64; d <<= 1) pk |= __shfl_xor(pk, d);
    prefix = (prefix << 8) | (pk & 255u);
    rem = pk >> 8;
  }
  const unsigned int Tkey = prefix;
  const unsigned int rem_final = rem;

  const unsigned long long below = (1ull << l) - 1ull;
  int basec = 0;
  unsigned int eq_seen = 0;
  for (int i = 0; i < 32; ++i) {
    int j = i * 64 + l;
    unsigned int k = key[i];
    bool gt = k > Tkey;
    bool eq = (k == Tkey);
    unsigned long long em = __ballot(eq);
    unsigned int eq_before = eq_seen + (unsigned)__popcll(em & below);
    bool sel = gt || (eq && (eq_before < rem_final));
    unsigned long long sm = __ballot(sel);
    int pos = basec + (int)__popcll(sm & below);
    if (sel) sel_s[w][pos] = j;
    basec += (int)__popcll(sm);
    eq_seen += (unsigned)__popcll(em);
  }

  float4 c4 = make_float4(0.f, 0.f, 0.f, 0.f);
  const float4* wm4 = reinterpret_cast<const float4*>(WmT);
  for (int k = 0; k < K_ACT; ++k) {
    int j = sel_s[w][k];
    float v = proj_s[w][j];
    fma4(c4, v, wm4[j * 64 + l]);
  }
  reinterpret_cast<float4*>(cue_g)[(size_t)(row0 + w) * 64 + l] = c4;
}

// ===== MFMA tile helper: acc[mt][nt] += A(state/ec rows) x B(weights) ======
// A in LDS (hi/lo, XOR-swizzled, row stride RLEN ushorts); B global row-major
// [n][RLEN] hi/lo. Lane mapping: A m=l&15, B n=l&15, k-set = 8*(l>>4)+i
// (+32*ks) — same formula both sides => contraction correct for any internal
// permutation. 3-term split: ah*bh + al*bh + ah*bl.
template <int NKS, int RLEN>
__device__ __forceinline__ void mm_tiles(
    const ushort* __restrict__ Bh, const ushort* __restrict__ Bl,
    const ushort* Ah, const ushort* Al, int w, int lg, int ln,
    f32x4 acc[2][4]) {
#pragma unroll
  for (int ks = 0; ks < NKS; ++ks) {
    const int k0 = 8 * lg + 32 * ks;
    short8v ah[2], al[2];
#pragma unroll
    for (int mt = 0; mt < 2; ++mt) {
      int m = mt * 16 + ln;
      int idx = m * RLEN + (k0 ^ (8 * (m & 7)));
      ah[mt] = *(const short8v*)&Ah[idx];
      al[mt] = *(const short8v*)&Al[idx];
    }
#pragma unroll
    for (int nt = 0; nt < 4; ++nt) {
      int n = ln + 16 * (4 * w + nt);
      short8v bh = *(const short8v*)&Bh[n * RLEN + k0];
      short8v bl = *(const short8v*)&Bl[n * RLEN + k0];
#pragma unroll
      for (int mt = 0; mt < 2; ++mt) {
        acc[mt][nt] = __builtin_amdgcn_mfma_f32_16x16x32_bf16(ah[mt], bh, acc[mt][nt], 0, 0, 0);
        acc[mt][nt] = __builtin_amdgcn_mfma_f32_16x16x32_bf16(al[mt], bh, acc[mt][nt], 0, 0, 0);
        acc[mt][nt] = __builtin_amdgcn_mfma_f32_16x16x32_bf16(ah[mt], bl, acc[mt][nt], 0, 0, 0);
      }
    }
  }
}

// ============ mega2: MFMA settle + fused MFMA epilogue =====================
// Block = 32 rows, 256 thr (4 waves). Wave w owns N-chunk [64w,64w+64).
// State/ec in LDS as bf16 hi/lo pairs (3-term split ~= fp32 precision).
__global__ __launch_bounds__(256, 3) void mega2(
    const float* __restrict__ coords, const float* __restrict__ colsum,
    const float* __restrict__ ec_gamma, const float* __restrict__ ec_beta,
    const float* __restrict__ cue_g,
    const ushort* __restrict__ Wrh, const ushort* __restrict__ Wrl,
    const ushort* __restrict__ F1h, const ushort* __restrict__ F1l, const float* __restrict__ c1,
    const ushort* __restrict__ F2h, const ushort* __restrict__ F2l, const float* __restrict__ c2,
    const ushort* __restrict__ F3h, const ushort* __restrict__ F3l, const float* __restrict__ c3,
    const ushort* __restrict__ F4h, const ushort* __restrict__ F4l, const float* __restrict__ c4v,
    const float* __restrict__ b_og, float* __restrict__ out) {
  __shared__ ushort st_h[32 * 256];
  __shared__ ushort st_l[32 * 256];
  __shared__ ushort ec_h[32 * 64];
  __shared__ ushort ec_l[32 * 64];
  __shared__ float novp[4][32][3];
  __shared__ float nov_s[32];

  const int t = threadIdx.x;
  const int w = t >> 6;
  const int l = t & 63;
  const int lg = l >> 4;
  const int ln = l & 15;
  const int row0 = blockIdx.x * 32;

  // ---- EC layernorm -> LDS bf16 hi/lo (wave w -> rows 8w..8w+7) ----
#pragma unroll 1
  for (int r = 0; r < 8; ++r) {
    int m = w * 8 + r;
    float x = coords[(size_t)(row0 + m) * COORD + l] + (0.05f / (float)B_N) * colsum[l];
    float mu = wave_sum(x) * (1.f / 64.f);
    float d = x - mu;
    float var = wave_sum(d * d) * (1.f / 64.f);
    float e = d * rsqrtf(var + LN_EPS) * ec_gamma[l] + ec_beta[l];
    ushort h = f2bf(e);
    int idx = m * 64 + (l ^ (8 * (m & 7)));
    ec_h[idx] = h;
    ec_l[idx] = f2bf(e - bf2f(h));
  }

  // ---- cue -> st LDS (bf16 hi/lo), thread t: row t/8, cols (t%8)*32.. ----
  {
    int r = t >> 3;
    int c0 = (t & 7) * 32;
#pragma unroll
    for (int cc = 0; cc < 32; cc += 8) {
      int c = c0 + cc;
      const float* src = &cue_g[(size_t)(row0 + r) * CA + c];
      short8v vh, vl;
#pragma unroll
      for (int j = 0; j < 8; ++j) {
        float v = src[j];
        ushort h = f2bf(v);
        vh[j] = (short)h;
        vl[j] = (short)f2bf(v - bf2f(h));
      }
      int idx = r * 256 + (c ^ (8 * (r & 7)));
      *(short8v*)&st_h[idx] = vh;
      *(short8v*)&st_l[idx] = vl;
    }
  }

  // ---- cue in C-layout registers for the settle update ----
  float cue_c[2][4][4];
#pragma unroll
  for (int mt = 0; mt < 2; ++mt)
#pragma unroll
    for (int nt = 0; nt < 4; ++nt)
#pragma unroll
      for (int r = 0; r < 4; ++r)
        cue_c[mt][nt][r] = cue_g[(size_t)(row0 + mt * 16 + lg * 4 + r) * CA +
                                 ln + 16 * (4 * w + nt)];
  __syncthreads();

  // ---- settle x5 ----
#pragma unroll 1
  for (int it = 0; it < SETTLE_STEPS; ++it) {
    f32x4 acc[2][4];
#pragma unroll
    for (int mt = 0; mt < 2; ++mt)
#pragma unroll
      for (int nt = 0; nt < 4; ++nt) acc[mt][nt] = f32x4{0.f, 0.f, 0.f, 0.f};
    mm_tiles<8, 256>(Wrh, Wrl, st_h, st_l, w, lg, ln, acc);
    __syncthreads();  // all reads of st done before overwrite
#pragma unroll
    for (int mt = 0; mt < 2; ++mt)
#pragma unroll
      for (int nt = 0; nt < 4; ++nt)
#pragma unroll
        for (int r = 0; r < 4; ++r) {
          float v = fast_tanh(GAIN * acc[mt][nt][r] + (1.f - GAIN) * cue_c[mt][nt][r]);
          int m = mt * 16 + lg * 4 + r;
          int n = ln + 16 * (4 * w + nt);
          int idx = m * 256 + (n ^ (8 * (m & 7)));
          ushort h = f2bf(v);
          st_h[idx] = h;
          st_l[idx] = f2bf(v - bf2f(h));
        }
    __syncthreads();
  }

  // ---- s_proj = state@F1^T + c1 ; d_proj = ec@F2^T + c2 ----
  f32x4 sp[2][4], dp[2][4];
#pragma unroll
  for (int mt = 0; mt < 2; ++mt)
#pragma unroll
    for (int nt = 0; nt < 4; ++nt) {
      sp[mt][nt] = f32x4{0.f, 0.f, 0.f, 0.f};
      dp[mt][nt] = f32x4{0.f, 0.f, 0.f, 0.f};
    }
  mm_tiles<8, 256>(F1h, F1l, st_h, st_l, w, lg, ln, sp);
  mm_tiles<2, 64>(F2h, F2l, ec_h, ec_l, w, lg, ln, dp);
#pragma unroll
  for (int nt = 0; nt < 4; ++nt) {
    int n = ln + 16 * (4 * w + nt);
    float a1 = c1[n], a2 = c2[n];
#pragma unroll
    for (int mt = 0; mt < 2; ++mt)
#pragma unroll
      for (int r = 0; r < 4; ++r) {
        sp[mt][nt][r] += a1;
        dp[mt][nt][r] += a2;
      }
  }

  // ---- novelty partials: per (mt,r) reduce over nt then over 16 lanes ----
#pragma unroll
  for (int mt = 0; mt < 2; ++mt)
#pragma unroll
    for (int r = 0; r < 4; ++r) {
      float psd = 0.f, psn = 0.f, pdn = 0.f;
#pragma unroll
      for (int nt = 0; nt < 4; ++nt) {
        psd += sp[mt][nt][r] * dp[mt][nt][r];
        psn += sp[mt][nt][r] * sp[mt][nt][r];
        pdn += dp[mt][nt][r] * dp[mt][nt][r];
      }
#pragma unroll
      for (int d = 1; d < 16; d <<= 1) {
        psd += __shfl_xor(psd, d);
        psn += __shfl_xor(psn, d);
        pdn += __shfl_xor(pdn, d);
      }
      if (ln == 0) {
        int m = mt * 16 + lg * 4 + r;
        novp[w][m][0] = psd;
        novp[w][m][1] = psn;
        novp[w][m][2] = pdn;
      }
    }
  __syncthreads();
  if (t < 32) {
    float sd = 0.f, sn = 0.f, dn = 0.f;
#pragma unroll
    for (int w2 = 0; w2 < 4; ++w2) {
      sd += novp[w2][t][0];
      sn += novp[w2][t][1];
      dn += novp[w2][t][2];
    }
    float s_n = fmaxf(sqrtf(sn), COS_EPS);
    float d_n = fmaxf(sqrtf(dn), COS_EPS);
    float nov = fminf(fmaxf(1.f - sd / (s_n * d_n), 0.f), 1.f);
    nov_s[t] = nov;
    out[(size_t)B_N * CA + row0 + t] = nov;
  }
  __syncthreads();

  // ---- o1 = state@F3^T + c3 ; o2 = ec@F4^T + c4 ; combine + store ----
  {
    f32x4 o1[2][4], o2[2][4];
#pragma unroll
    for (int mt = 0; mt < 2; ++mt)
#pragma unroll
      for (int nt = 0; nt < 4; ++nt) {
        o1[mt][nt] = f32x4{0.f, 0.f, 0.f, 0.f};
        o2[mt][nt] = f32x4{0.f, 0.f, 0.f, 0.f};
      }
    mm_tiles<8, 256>(F3h, F3l, st_h, st_l, w, lg, ln, o1);
    mm_tiles<2, 64>(F4h, F4l, ec_h, ec_l, w, lg, ln, o2);
#pragma unroll
    for (int nt = 0; nt < 4; ++nt) {
      int n = ln + 16 * (4 * w + nt);
      float a3 = c3[n], a4 = c4v[n], bo = b_og[n];
#pragma unroll
      for (int mt = 0; mt < 2; ++mt)
#pragma unroll
        for (int r = 0; r < 4; ++r) {
          int m = mt * 16 + lg * 4 + r;
          float g = nov_s[m];
          float o = fast_tanh(g * (o2[mt][nt][r] + a4) +
                              (1.f - g) * (o1[mt][nt][r] + a3) + bo);
          out[(size_t)(row0 + m) * CA + n] = o;
        }
    }
  }
}

extern "C" void kernel_launch(void* const* d_in, const int* in_sizes, int n_in,
                              void* d_out, int out_size, void* d_ws,
                              size_t ws_size, hipStream_t stream) {
  const float* coords = (const float*)d_in[0];
  const float* ec_gamma = (const float*)d_in[1];
  const float* ec_beta = (const float*)d_in[2];
  const float* W_pp = (const float*)d_in[3];
  const float* b_pp = (const float*)d_in[4];
  const float* dg_gamma = (const float*)d_in[5];
  const float* dg_beta = (const float*)d_in[6];
  const float* W_mossy = (const float*)d_in[7];
  const float* W_rec = (const float*)d_in[8];
  const float* W_sc = (const float*)d_in[9];
  const float* b_sc = (const float*)d_in[10];
  const float* W_ta = (const float*)d_in[11];
  const float* b_ta = (const float*)d_in[12];
  const float* W_cs = (const float*)d_in[13];
  const float* W_cd = (const float*)d_in[14];
  const float* W_og = (const float*)d_in[15];
  const float* b_og = (const float*)d_in[16];
  float* out = (float*)d_out;

  float* ws = (float*)d_ws;
  float* colsum = ws;                        // 64
  float* WmT    = colsum + 64;               // 2048*256
  float* W_ppT  = WmT + 2048 * 256;          // 64*2048
  float* W_scT  = W_ppT + 64 * 2048;         // 256*256
  float* W_taT  = W_scT + 256 * 256;         // 64*256
  float* c1     = W_taT + 64 * 256;          // 256
  float* c2     = c1 + 256;                  // 256
  float* c3     = c2 + 256;                  // 256
  float* c4     = c3 + 256;                  // 256
  ushort* us    = (ushort*)(c4 + 256);
  ushort* Wrh   = us;                        // 65536
  ushort* Wrl   = Wrh + 65536;
  ushort* F1h   = Wrl + 65536;               // 65536
  ushort* F1l   = F1h + 65536;
  ushort* F3h   = F1l + 65536;               // 65536
  ushort* F3l   = F3h + 65536;
  ushort* F2h   = F3l + 65536;               // 16384
  ushort* F2l   = F2h + 16384;
  ushort* F4h   = F2l + 16384;               // 16384
  ushort* F4l   = F4h + 16384;
  float* cue_g  = (float*)(F4l + 16384);     // 32768*256

  hipMemsetAsync(colsum, 0, COORD * sizeof(float), stream);
  colsum_kernel<<<256, 256, 0, stream>>>(coords, colsum);
  transpose_any<<<(256 * 2048 + 255) / 256, 256, 0, stream>>>(W_mossy, WmT, 256, 2048);
  transpose_any<<<(2048 * 64 + 255) / 256, 256, 0, stream>>>(W_pp, W_ppT, 2048, 64);
  transpose_any<<<(256 * 256 + 255) / 256, 256, 0, stream>>>(W_sc, W_scT, 256, 256);
  transpose_any<<<(256 * 64 + 255) / 256, 256, 0, stream>>>(W_ta, W_taT, 256, 64);

  split_bf16<<<256, 256, 0, stream>>>(W_rec, Wrh, Wrl, 256 * 256);
  fuse_mm_bf16<<<256, 256, 0, stream>>>(W_cs, W_scT, b_sc, F1h, F1l, c1, 256);
  fuse_mm_bf16<<<64, 256, 0, stream>>>(W_cd, W_taT, b_ta, F2h, F2l, c2, 64);
  fuse_mm_bf16<<<256, 256, 0, stream>>>(W_og, W_scT, b_sc, F3h, F3l, c3, 256);
  fuse_mm_bf16<<<64, 256, 0, stream>>>(W_og, W_taT, b_ta, F4h, F4l, c4, 64);

  mega1<<<B_N / 8, 512, 0, stream>>>(coords, colsum, ec_gamma, ec_beta, W_ppT,
                                     b_pp, dg_gamma, dg_beta, WmT, cue_g);
  mega2<<<B_N / 32, 256, 0, stream>>>(coords, colsum, ec_gamma, ec_beta, cue_g,
                                      Wrh, Wrl, F1h, F1l, c1, F2h, F2l, c2,
                                      F3h, F3l, c3, F4h, F4l, c4, b_og, out);
}